// Round 5
// baseline (604.510 us; speedup 1.0000x reference)
//
#include <hip/hip_runtime.h>

// out[r*64+ch] = b[ch] + sum_{edges (r,c)} W[ch][c],  r normalized by row.min().
// N = 100000, C = 64, E = 3.2M.
//
// R5: R4 structure (XCD-sharded fill + bf16 Wt gather) with the analyze scan
//     rewritten as a single branch-free uint4 pass (R4's was latency-serialized
//     at 153us for 25.6MB). Gather col-list loads vectorized to int4.
// ws: flags[256 int] | cur[N int] | Wtb[N*64 bf16] | ovf[OVF_MAX*2 int] | cols[N*64 int]

#define OVF_MAX (1 << 19)
#define CAP 64          // slots per row; Poisson(32) => P(overflow) ~ 1e-7 per row
#define NSHARD 8        // one shard per XCD (blockIdx % 8 round-robin heuristic)

__device__ __forceinline__ float bf16u_to_f(unsigned short u) {
    union { unsigned int i; float f; } x; x.i = ((unsigned int)u) << 16; return x.f;
}

__global__ void LINK_init_kernel(int* __restrict__ cur, int* __restrict__ flags, int N) {
    int i = blockIdx.x * blockDim.x + threadIdx.x;
    if (i == 0) { flags[0] = 0; flags[1] = 0x7fffffff; flags[2] = 0x7fffffff; flags[8] = 0; }
    if (i < N) cur[i] = i << 6;  // i * CAP
}

// Single branch-free uint4 pass over all 2E words:
//   oddOr: OR of odd words (int64 -> 0), mn64: min of even words,
//   mn32: min over words[0..E) (first quarter of the uint4 range, uniform branch).
__global__ __launch_bounds__(256) void LINK_analyze_kernel(
    const unsigned int* __restrict__ words, int E, int* __restrict__ flags) {
    const uint4* __restrict__ w4 = (const uint4*)words;
    int tid = blockIdx.x * blockDim.x + threadIdx.x;
    int nth = gridDim.x * blockDim.x;
    int n1 = E >> 2;            // uint4s fully inside [0, E)
    long long twoE = 2LL * E;
    int n2 = (int)(twoE >> 2);  // uint4s fully inside [0, 2E)
    unsigned int oddOr = 0u;
    int mn32 = 0x7fffffff, mn64 = 0x7fffffff;
    for (int i = tid; i < n2; i += nth) {
        uint4 w = w4[i];
        oddOr |= (w.y | w.w);
        mn64 = min(mn64, min((int)w.x, (int)w.z));
        if (i < n1) {
            int a = min((int)w.x, (int)w.y);
            int c = min((int)w.z, (int)w.w);
            mn32 = min(mn32, min(a, c));
        }
    }
    // scalar tails (E not divisible by 4)
    for (long long i = ((long long)n1 << 2) + tid; i < E; i += nth)
        mn32 = min(mn32, (int)words[i]);
    for (long long i = ((long long)n2 << 2) + tid; i < twoE; i += nth) {
        unsigned int w = words[i];
        if (i & 1) oddOr |= w; else mn64 = min(mn64, (int)w);
    }
    for (int off = 32; off > 0; off >>= 1) {
        oddOr |= (unsigned int)__shfl_down((int)oddOr, off, 64);
        mn32 = min(mn32, __shfl_down(mn32, off, 64));
        mn64 = min(mn64, __shfl_down(mn64, off, 64));
    }
    if ((threadIdx.x & 63) == 0) {
        if (oddOr) atomicOr(&flags[0], 1);
        atomicMin(&flags[1], mn32);
        atomicMin(&flags[2], mn64);
    }
}

// W [64][N] f32 -> Wtb [N][64] bf16 (RNE) via padded LDS tile.
__global__ void LINK_transpose_kernel(const float* __restrict__ W,
                                      unsigned short* __restrict__ Wtb, int N) {
    __shared__ float tile[64][65];
    int n0 = blockIdx.x * 64;
    int lx = threadIdx.x & 63;
    int ly = threadIdx.x >> 6;
#pragma unroll
    for (int it = 0; it < 16; ++it) {
        int ch = ly + 4 * it;
        float v = 0.0f;
        if (n0 + lx < N) v = W[(size_t)ch * N + (n0 + lx)];
        tile[lx][ch] = v;
    }
    __syncthreads();
#pragma unroll
    for (int it = 0; it < 16; ++it) {
        int nn = ly + 4 * it;
        if (n0 + nn < N) {
            union { float f; unsigned int i; } x; x.f = tile[nn][lx];
            unsigned int u = x.i;
            unsigned int r = (u + 0x7fffu + ((u >> 16) & 1u)) >> 16;  // RNE
            Wtb[((size_t)(n0 + nn) << 6) + lx] = (unsigned short)r;
        }
    }
}

// XCD-sharded CSR fill: block b owns row shard (b & 7). Each shard's cols region
// (12500 rows * 64 slots * 4B = 3.2MB) stays resident in one XCD's L2.
__global__ __launch_bounds__(256) void LINK_fill_kernel(
    const unsigned int* __restrict__ words, int E, int N,
    int* __restrict__ cur, int* __restrict__ cols,
    int* __restrict__ ovf, int* __restrict__ flags) {
    int shard = blockIdx.x & (NSHARD - 1);
    int qb = blockIdx.x >> 3;
    int Q = gridDim.x >> 3;
    int rows_per = (N + NSHARD - 1) / NSHARD;
    int rlo = shard * rows_per;
    int rhi = min(N, rlo + rows_per);
    int isInt32 = flags[0];
    long long i0 = (long long)qb * blockDim.x + threadIdx.x;
    long long stride = (long long)Q * blockDim.x;
    for (long long e = i0; e < E; e += stride) {
        int r = isInt32 ? (int)words[e] : (int)words[2 * e];
        if (r < rlo || r >= rhi) continue;
        int c = isInt32 ? (int)words[E + e] : (int)words[2LL * E + 2 * e];
        if ((unsigned)c >= (unsigned)N) continue;
        int pos = atomicAdd(&cur[r], 1);
        if (pos - (r << 6) < CAP) {
            cols[pos] = c;
        } else {
            int oi = atomicAdd(&flags[8], 1);
            if (oi < OVF_MAX) { ovf[2 * oi] = r; ovf[2 * oi + 1] = c; }
        }
    }
}

// One wave per output row; lane = channel. bf16 Wt rows (128B coalesced), fp32 acc,
// 8 independent Wtb loads in flight; col lists read as wave-uniform int4.
__global__ __launch_bounds__(256) void LINK_gather_kernel(
    const int* __restrict__ cur, const int* __restrict__ cols,
    const unsigned short* __restrict__ Wtb, const float* __restrict__ b,
    float* __restrict__ out, const int* __restrict__ flags, int N) {
    int g = blockIdx.x * blockDim.x + threadIdx.x;
    int row = g >> 6;
    int lane = g & 63;
    if (row >= N) return;
    int rmin = flags[0] ? flags[1] : flags[2];
    float acc = 0.0f;
    long long raw = (long long)row + rmin;
    if (raw >= 0 && raw < N) {
        int base = (int)raw << 6;
        int len = cur[raw] - base;
        if (len > CAP) len = CAP;
        const int4* cp4 = (const int4*)(cols + base);  // 256B-aligned
        int j = 0;
        for (; j + 8 <= len; j += 8) {
            int4 q0 = cp4[(j >> 2) + 0];
            int4 q1 = cp4[(j >> 2) + 1];
            unsigned short u0 = Wtb[((size_t)q0.x << 6) + lane];
            unsigned short u1 = Wtb[((size_t)q0.y << 6) + lane];
            unsigned short u2 = Wtb[((size_t)q0.z << 6) + lane];
            unsigned short u3 = Wtb[((size_t)q0.w << 6) + lane];
            unsigned short u4 = Wtb[((size_t)q1.x << 6) + lane];
            unsigned short u5 = Wtb[((size_t)q1.y << 6) + lane];
            unsigned short u6 = Wtb[((size_t)q1.z << 6) + lane];
            unsigned short u7 = Wtb[((size_t)q1.w << 6) + lane];
            float s01 = bf16u_to_f(u0) + bf16u_to_f(u1);
            float s23 = bf16u_to_f(u2) + bf16u_to_f(u3);
            float s45 = bf16u_to_f(u4) + bf16u_to_f(u5);
            float s67 = bf16u_to_f(u6) + bf16u_to_f(u7);
            acc += (s01 + s23) + (s45 + s67);
        }
        const int* cp = cols + base;
        for (; j < len; ++j)
            acc += bf16u_to_f(Wtb[((size_t)cp[j] << 6) + lane]);
    }
    out[((size_t)row << 6) + lane] = acc + b[lane];
}

// Cleanup for spilled edges (expected zero on real data).
__global__ void LINK_ovf_kernel(const int* __restrict__ ovf, const int* __restrict__ flags,
                                const unsigned short* __restrict__ Wtb,
                                float* __restrict__ out, int N) {
    int g = blockIdx.x * blockDim.x + threadIdx.x;
    int w = g >> 6, lane = g & 63;
    int cnt = flags[8]; if (cnt > OVF_MAX) cnt = OVF_MAX;
    if (cnt == 0) return;
    int rmin = flags[0] ? flags[1] : flags[2];
    int nw = (gridDim.x * blockDim.x) >> 6;
    for (int i = w; i < cnt; i += nw) {
        int r = ovf[2 * i] - rmin;
        int c = ovf[2 * i + 1];
        if ((unsigned)r >= (unsigned)N || (unsigned)c >= (unsigned)N) continue;
        atomicAdd(&out[((size_t)r << 6) + lane], bf16u_to_f(Wtb[((size_t)c << 6) + lane]));
    }
}

// ---- Fallback (R1): bias init + wave-per-edge fp-atomic scatter on raw W ----
__global__ void LINK_initout_kernel(float* __restrict__ out, const float* __restrict__ b,
                                    int total, int* __restrict__ flags) {
    int i = blockIdx.x * blockDim.x + threadIdx.x;
    if (i == 0) { flags[0] = 0; flags[1] = 0x7fffffff; flags[2] = 0x7fffffff; }
    if (i < total) out[i] = b[i & 63];
}

__global__ void LINK_scatter_kernel(const unsigned int* __restrict__ words, int E,
                                    const float* __restrict__ W,
                                    float* __restrict__ out,
                                    const int* __restrict__ flags, int N) {
    long long g = (long long)blockIdx.x * blockDim.x + threadIdx.x;
    int e = (int)(g >> 6);
    if (e >= E) return;
    int ch = (int)(g & 63);
    int r, c, rmin;
    if (flags[0]) { r = (int)words[e]; c = (int)words[E + e]; rmin = flags[1]; }
    else { r = (int)words[2LL * e]; c = (int)words[2LL * (E + e)]; rmin = flags[2]; }
    r -= rmin;
    if ((unsigned)r >= (unsigned)N || (unsigned)c >= (unsigned)N) return;
    atomicAdd(&out[((size_t)r << 6) + ch], W[(size_t)ch * N + c]);
}

static inline size_t align256(size_t x) { return (x + 255) & ~(size_t)255; }

extern "C" void kernel_launch(void* const* d_in, const int* in_sizes, int n_in,
                              void* d_out, int out_size, void* d_ws, size_t ws_size,
                              hipStream_t stream) {
    const unsigned int* words = (const unsigned int*)d_in[0];
    const float* W = (const float*)d_in[1];
    const float* b = (const float*)d_in[2];
    float* out = (float*)d_out;

    int E = in_sizes[0] / 2;   // 3,200,000
    int N = in_sizes[1] / 64;  // 100,000
    int total = out_size;      // N*64

    size_t off_flags = 0;
    size_t off_cur   = align256(off_flags + 256 * sizeof(int));
    size_t off_wtb   = align256(off_cur + (size_t)N * sizeof(int));
    size_t off_ovf   = align256(off_wtb + (size_t)N * 64 * sizeof(unsigned short));
    size_t off_cols  = align256(off_ovf + (size_t)OVF_MAX * 2 * sizeof(int));
    size_t need      = off_cols + (size_t)N * CAP * sizeof(int);

    int* flags = (int*)((char*)d_ws + off_flags);
    int* cur   = (int*)((char*)d_ws + off_cur);
    unsigned short* Wtb = (unsigned short*)((char*)d_ws + off_wtb);
    int* ovf   = (int*)((char*)d_ws + off_ovf);
    int* cols  = (int*)((char*)d_ws + off_cols);

    if (ws_size >= need) {
        LINK_init_kernel<<<(N + 255) / 256, 256, 0, stream>>>(cur, flags, N);
        LINK_analyze_kernel<<<2048, 256, 0, stream>>>(words, E, flags);
        LINK_transpose_kernel<<<(N + 63) / 64, 256, 0, stream>>>(W, Wtb, N);
        LINK_fill_kernel<<<2048, 256, 0, stream>>>(words, E, N, cur, cols, ovf, flags);
        long long gthreads = (long long)N * 64;
        LINK_gather_kernel<<<(int)((gthreads + 255) / 256), 256, 0, stream>>>(
            cur, cols, Wtb, b, out, flags, N);
        LINK_ovf_kernel<<<64, 256, 0, stream>>>(ovf, flags, Wtb, out, N);
    } else {
        LINK_initout_kernel<<<(total + 255) / 256, 256, 0, stream>>>(out, b, total, flags);
        LINK_analyze_kernel<<<2048, 256, 0, stream>>>(words, E, flags);
        long long tthreads = (long long)E * 64;
        LINK_scatter_kernel<<<(int)((tthreads + 255) / 256), 256, 0, stream>>>(
            words, E, W, out, flags, N);
    }
}

// Round 6
// 335.185 us; speedup vs baseline: 1.8035x; 1.8035x over previous
//
#include <hip/hip_runtime.h>

// out[r*64+ch] = b[ch] + sum_{edges (r,c)} W[ch][c],  r normalized by row.min().
// N = 100000, C = 64, E = 3.2M.
//
// R6: R5 structure; analyze rewritten with block-level reduction (one atomic
//     triple per block, 768 total vs 24576 — R5 was serialized at ~12ns per
//     same-cache-line atomic RMW, scaling linearly with wave count).
// ws: flags[256 int] | cur[N int] | Wtb[N*64 bf16] | ovf[OVF_MAX*2 int] | cols[N*64 int]

#define OVF_MAX (1 << 19)
#define CAP 64          // slots per row; Poisson(32) => P(overflow) ~ 1e-7 per row
#define NSHARD 8        // one shard per XCD (blockIdx % 8 round-robin heuristic)

__device__ __forceinline__ float bf16u_to_f(unsigned short u) {
    union { unsigned int i; float f; } x; x.i = ((unsigned int)u) << 16; return x.f;
}

__global__ void LINK_init_kernel(int* __restrict__ cur, int* __restrict__ flags, int N) {
    int i = blockIdx.x * blockDim.x + threadIdx.x;
    if (i == 0) { flags[0] = 0; flags[1] = 0x7fffffff; flags[2] = 0x7fffffff; flags[8] = 0; }
    if (i < N) cur[i] = i << 6;  // i * CAP
}

// Full scan of words[0..2E): oddOr (dtype detect), mn64 (even words),
// mn32 (words[0..E)). 4 independent uint4 loads in flight; ONE atomic triple
// per block (block-level LDS reduction) to avoid same-line atomic serialization.
__global__ __launch_bounds__(256) void LINK_analyze_kernel(
    const unsigned int* __restrict__ words, int E, int* __restrict__ flags) {
    const uint4* __restrict__ w4 = (const uint4*)words;
    int tid = blockIdx.x * blockDim.x + threadIdx.x;
    int nth = gridDim.x * blockDim.x;
    int n1 = E >> 2;            // uint4s fully inside [0, E)
    long long twoE = 2LL * E;
    int n2 = (int)(twoE >> 2);  // uint4s fully inside [0, 2E)
    unsigned int oddOr = 0u;
    int mn32 = 0x7fffffff, mn64 = 0x7fffffff;
    // segment 1: [0, n1) — contributes to mn32, mn64, oddOr
    {
        int i = tid;
        for (; i + 3 * nth < n1; i += 4 * nth) {
            uint4 a = w4[i], b = w4[i + nth], c = w4[i + 2 * nth], d = w4[i + 3 * nth];
            oddOr |= (a.y | a.w) | (b.y | b.w) | (c.y | c.w) | (d.y | d.w);
            int m1 = min(min((int)a.x, (int)a.z), min((int)b.x, (int)b.z));
            int m2 = min(min((int)c.x, (int)c.z), min((int)d.x, (int)d.z));
            mn64 = min(mn64, min(m1, m2));
            int p1 = min(min((int)a.x, (int)a.y), min((int)a.z, (int)a.w));
            int p2 = min(min((int)b.x, (int)b.y), min((int)b.z, (int)b.w));
            int p3 = min(min((int)c.x, (int)c.y), min((int)c.z, (int)c.w));
            int p4 = min(min((int)d.x, (int)d.y), min((int)d.z, (int)d.w));
            mn32 = min(mn32, min(min(p1, p2), min(p3, p4)));
        }
        for (; i < n1; i += nth) {
            uint4 a = w4[i];
            oddOr |= (a.y | a.w);
            mn64 = min(mn64, min((int)a.x, (int)a.z));
            mn32 = min(mn32, min(min((int)a.x, (int)a.y), min((int)a.z, (int)a.w)));
        }
    }
    // segment 2: [n1, n2) — mn64, oddOr only
    {
        int i = n1 + tid;
        for (; i + 3 * nth < n2; i += 4 * nth) {
            uint4 a = w4[i], b = w4[i + nth], c = w4[i + 2 * nth], d = w4[i + 3 * nth];
            oddOr |= (a.y | a.w) | (b.y | b.w) | (c.y | c.w) | (d.y | d.w);
            int m1 = min(min((int)a.x, (int)a.z), min((int)b.x, (int)b.z));
            int m2 = min(min((int)c.x, (int)c.z), min((int)d.x, (int)d.z));
            mn64 = min(mn64, min(m1, m2));
        }
        for (; i < n2; i += nth) {
            uint4 a = w4[i];
            oddOr |= (a.y | a.w);
            mn64 = min(mn64, min((int)a.x, (int)a.z));
        }
    }
    // scalar tails (E not divisible by 4)
    for (long long i = ((long long)n1 << 2) + tid; i < E; i += nth)
        mn32 = min(mn32, (int)words[i]);
    for (long long i = ((long long)n2 << 2) + tid; i < twoE; i += nth) {
        unsigned int w = words[i];
        if (i & 1) oddOr |= w; else mn64 = min(mn64, (int)w);
    }
    // wave reduction
    for (int off = 32; off > 0; off >>= 1) {
        oddOr |= (unsigned int)__shfl_down((int)oddOr, off, 64);
        mn32 = min(mn32, __shfl_down(mn32, off, 64));
        mn64 = min(mn64, __shfl_down(mn64, off, 64));
    }
    // block reduction across 4 waves -> single atomic triple per block
    __shared__ int s_or[4], s_m32[4], s_m64[4];
    int wid = threadIdx.x >> 6;
    if ((threadIdx.x & 63) == 0) {
        s_or[wid] = (int)oddOr; s_m32[wid] = mn32; s_m64[wid] = mn64;
    }
    __syncthreads();
    if (threadIdx.x == 0) {
        int o = s_or[0] | s_or[1] | s_or[2] | s_or[3];
        int a = min(min(s_m32[0], s_m32[1]), min(s_m32[2], s_m32[3]));
        int d = min(min(s_m64[0], s_m64[1]), min(s_m64[2], s_m64[3]));
        if (o) atomicOr(&flags[0], 1);
        atomicMin(&flags[1], a);
        atomicMin(&flags[2], d);
    }
}

// W [64][N] f32 -> Wtb [N][64] bf16 (RNE) via padded LDS tile.
__global__ void LINK_transpose_kernel(const float* __restrict__ W,
                                      unsigned short* __restrict__ Wtb, int N) {
    __shared__ float tile[64][65];
    int n0 = blockIdx.x * 64;
    int lx = threadIdx.x & 63;
    int ly = threadIdx.x >> 6;
#pragma unroll
    for (int it = 0; it < 16; ++it) {
        int ch = ly + 4 * it;
        float v = 0.0f;
        if (n0 + lx < N) v = W[(size_t)ch * N + (n0 + lx)];
        tile[lx][ch] = v;
    }
    __syncthreads();
#pragma unroll
    for (int it = 0; it < 16; ++it) {
        int nn = ly + 4 * it;
        if (n0 + nn < N) {
            union { float f; unsigned int i; } x; x.f = tile[nn][lx];
            unsigned int u = x.i;
            unsigned int r = (u + 0x7fffu + ((u >> 16) & 1u)) >> 16;  // RNE
            Wtb[((size_t)(n0 + nn) << 6) + lx] = (unsigned short)r;
        }
    }
}

// XCD-sharded CSR fill: block b owns row shard (b & 7). Each shard's cols region
// (12500 rows * 64 slots * 4B = 3.2MB) stays resident in one XCD's L2.
__global__ __launch_bounds__(256) void LINK_fill_kernel(
    const unsigned int* __restrict__ words, int E, int N,
    int* __restrict__ cur, int* __restrict__ cols,
    int* __restrict__ ovf, int* __restrict__ flags) {
    int shard = blockIdx.x & (NSHARD - 1);
    int qb = blockIdx.x >> 3;
    int Q = gridDim.x >> 3;
    int rows_per = (N + NSHARD - 1) / NSHARD;
    int rlo = shard * rows_per;
    int rhi = min(N, rlo + rows_per);
    int isInt32 = flags[0];
    long long i0 = (long long)qb * blockDim.x + threadIdx.x;
    long long stride = (long long)Q * blockDim.x;
    for (long long e = i0; e < E; e += stride) {
        int r = isInt32 ? (int)words[e] : (int)words[2 * e];
        if (r < rlo || r >= rhi) continue;
        int c = isInt32 ? (int)words[E + e] : (int)words[2LL * E + 2 * e];
        if ((unsigned)c >= (unsigned)N) continue;
        int pos = atomicAdd(&cur[r], 1);
        if (pos - (r << 6) < CAP) {
            cols[pos] = c;
        } else {
            int oi = atomicAdd(&flags[8], 1);
            if (oi < OVF_MAX) { ovf[2 * oi] = r; ovf[2 * oi + 1] = c; }
        }
    }
}

// One wave per output row; lane = channel. bf16 Wt rows (128B coalesced), fp32 acc,
// 8 independent Wtb loads in flight; col lists read as wave-uniform int4.
__global__ __launch_bounds__(256) void LINK_gather_kernel(
    const int* __restrict__ cur, const int* __restrict__ cols,
    const unsigned short* __restrict__ Wtb, const float* __restrict__ b,
    float* __restrict__ out, const int* __restrict__ flags, int N) {
    int g = blockIdx.x * blockDim.x + threadIdx.x;
    int row = g >> 6;
    int lane = g & 63;
    if (row >= N) return;
    int rmin = flags[0] ? flags[1] : flags[2];
    float acc = 0.0f;
    long long raw = (long long)row + rmin;
    if (raw >= 0 && raw < N) {
        int base = (int)raw << 6;
        int len = cur[raw] - base;
        if (len > CAP) len = CAP;
        const int4* cp4 = (const int4*)(cols + base);  // 256B-aligned
        int j = 0;
        for (; j + 8 <= len; j += 8) {
            int4 q0 = cp4[(j >> 2) + 0];
            int4 q1 = cp4[(j >> 2) + 1];
            unsigned short u0 = Wtb[((size_t)q0.x << 6) + lane];
            unsigned short u1 = Wtb[((size_t)q0.y << 6) + lane];
            unsigned short u2 = Wtb[((size_t)q0.z << 6) + lane];
            unsigned short u3 = Wtb[((size_t)q0.w << 6) + lane];
            unsigned short u4 = Wtb[((size_t)q1.x << 6) + lane];
            unsigned short u5 = Wtb[((size_t)q1.y << 6) + lane];
            unsigned short u6 = Wtb[((size_t)q1.z << 6) + lane];
            unsigned short u7 = Wtb[((size_t)q1.w << 6) + lane];
            float s01 = bf16u_to_f(u0) + bf16u_to_f(u1);
            float s23 = bf16u_to_f(u2) + bf16u_to_f(u3);
            float s45 = bf16u_to_f(u4) + bf16u_to_f(u5);
            float s67 = bf16u_to_f(u6) + bf16u_to_f(u7);
            acc += (s01 + s23) + (s45 + s67);
        }
        const int* cp = cols + base;
        for (; j < len; ++j)
            acc += bf16u_to_f(Wtb[((size_t)cp[j] << 6) + lane]);
    }
    out[((size_t)row << 6) + lane] = acc + b[lane];
}

// Cleanup for spilled edges (expected zero on real data).
__global__ void LINK_ovf_kernel(const int* __restrict__ ovf, const int* __restrict__ flags,
                                const unsigned short* __restrict__ Wtb,
                                float* __restrict__ out, int N) {
    int g = blockIdx.x * blockDim.x + threadIdx.x;
    int w = g >> 6, lane = g & 63;
    int cnt = flags[8]; if (cnt > OVF_MAX) cnt = OVF_MAX;
    if (cnt == 0) return;
    int rmin = flags[0] ? flags[1] : flags[2];
    int nw = (gridDim.x * blockDim.x) >> 6;
    for (int i = w; i < cnt; i += nw) {
        int r = ovf[2 * i] - rmin;
        int c = ovf[2 * i + 1];
        if ((unsigned)r >= (unsigned)N || (unsigned)c >= (unsigned)N) continue;
        atomicAdd(&out[((size_t)r << 6) + lane], bf16u_to_f(Wtb[((size_t)c << 6) + lane]));
    }
}

// ---- Fallback (R1): bias init + wave-per-edge fp-atomic scatter on raw W ----
__global__ void LINK_initout_kernel(float* __restrict__ out, const float* __restrict__ b,
                                    int total, int* __restrict__ flags) {
    int i = blockIdx.x * blockDim.x + threadIdx.x;
    if (i == 0) { flags[0] = 0; flags[1] = 0x7fffffff; flags[2] = 0x7fffffff; }
    if (i < total) out[i] = b[i & 63];
}

__global__ void LINK_scatter_kernel(const unsigned int* __restrict__ words, int E,
                                    const float* __restrict__ W,
                                    float* __restrict__ out,
                                    const int* __restrict__ flags, int N) {
    long long g = (long long)blockIdx.x * blockDim.x + threadIdx.x;
    int e = (int)(g >> 6);
    if (e >= E) return;
    int ch = (int)(g & 63);
    int r, c, rmin;
    if (flags[0]) { r = (int)words[e]; c = (int)words[E + e]; rmin = flags[1]; }
    else { r = (int)words[2LL * e]; c = (int)words[2LL * (E + e)]; rmin = flags[2]; }
    r -= rmin;
    if ((unsigned)r >= (unsigned)N || (unsigned)c >= (unsigned)N) return;
    atomicAdd(&out[((size_t)r << 6) + ch], W[(size_t)ch * N + c]);
}

static inline size_t align256(size_t x) { return (x + 255) & ~(size_t)255; }

extern "C" void kernel_launch(void* const* d_in, const int* in_sizes, int n_in,
                              void* d_out, int out_size, void* d_ws, size_t ws_size,
                              hipStream_t stream) {
    const unsigned int* words = (const unsigned int*)d_in[0];
    const float* W = (const float*)d_in[1];
    const float* b = (const float*)d_in[2];
    float* out = (float*)d_out;

    int E = in_sizes[0] / 2;   // 3,200,000
    int N = in_sizes[1] / 64;  // 100,000
    int total = out_size;      // N*64

    size_t off_flags = 0;
    size_t off_cur   = align256(off_flags + 256 * sizeof(int));
    size_t off_wtb   = align256(off_cur + (size_t)N * sizeof(int));
    size_t off_ovf   = align256(off_wtb + (size_t)N * 64 * sizeof(unsigned short));
    size_t off_cols  = align256(off_ovf + (size_t)OVF_MAX * 2 * sizeof(int));
    size_t need      = off_cols + (size_t)N * CAP * sizeof(int);

    int* flags = (int*)((char*)d_ws + off_flags);
    int* cur   = (int*)((char*)d_ws + off_cur);
    unsigned short* Wtb = (unsigned short*)((char*)d_ws + off_wtb);
    int* ovf   = (int*)((char*)d_ws + off_ovf);
    int* cols  = (int*)((char*)d_ws + off_cols);

    if (ws_size >= need) {
        LINK_init_kernel<<<(N + 255) / 256, 256, 0, stream>>>(cur, flags, N);
        LINK_analyze_kernel<<<256, 256, 0, stream>>>(words, E, flags);
        LINK_transpose_kernel<<<(N + 63) / 64, 256, 0, stream>>>(W, Wtb, N);
        LINK_fill_kernel<<<2048, 256, 0, stream>>>(words, E, N, cur, cols, ovf, flags);
        long long gthreads = (long long)N * 64;
        LINK_gather_kernel<<<(int)((gthreads + 255) / 256), 256, 0, stream>>>(
            cur, cols, Wtb, b, out, flags, N);
        LINK_ovf_kernel<<<64, 256, 0, stream>>>(ovf, flags, Wtb, out, N);
    } else {
        LINK_initout_kernel<<<(total + 255) / 256, 256, 0, stream>>>(out, b, total, flags);
        LINK_analyze_kernel<<<256, 256, 0, stream>>>(words, E, flags);
        long long tthreads = (long long)E * 64;
        LINK_scatter_kernel<<<(int)((tthreads + 255) / 256), 256, 0, stream>>>(
            words, E, W, out, flags, N);
    }
}